// Round 13
// baseline (46.828 us; speedup 1.0000x reference)
//
#include <hip/hip_runtime.h>
#include <hip/hip_bf16.h>

typedef __bf16 bf16;
typedef bf16  bf16x2 __attribute__((ext_vector_type(2)));
typedef bf16  bf16x4 __attribute__((ext_vector_type(4)));
typedef bf16  bf16x8 __attribute__((ext_vector_type(8)));
typedef float f32x4  __attribute__((ext_vector_type(4)));
typedef float f32x16 __attribute__((ext_vector_type(16)));

#define MFMA32(A, B, C) __builtin_amdgcn_mfma_f32_32x32x16_bf16((A), (B), (C), 0, 0, 0)

namespace {
constexpr int   kS = 2048, kHq = 16, kHkv = 8, kD = 128, kChunk = 512;
constexpr int   kStrK  = kHkv * kD;                      // floats between keys
constexpr float kLog2e = 1.4426950408889634f;
constexpr float kScale = 0.08838834764831845f * kLog2e;  // exp2-domain softmax
constexpr float kThr   = 8.0f * kLog2e;                  // T13 threshold (log2)
constexpr size_t kWsNeed = 2ull * 512 * 8192 * sizeof(bf16);  // 16 MB
}

union U32B { bf16x2 h; unsigned u; };
union PAU  { unsigned u[4]; bf16x8 v; };

__device__ __forceinline__ void glds16(const bf16* g, bf16* l) {
  __builtin_amdgcn_global_load_lds(
      (const __attribute__((address_space(1))) unsigned*)g,
      (__attribute__((address_space(3))) unsigned*)l, 16, 0, 0);
}
__device__ __forceinline__ void bar() {
  __builtin_amdgcn_sched_barrier(0);
  __builtin_amdgcn_s_barrier();
  __builtin_amdgcn_sched_barrier(0);
}
#define VMWAIT(n)                                          \
  do {                                                     \
    __builtin_amdgcn_sched_barrier(0);                     \
    asm volatile("s_waitcnt vmcnt(" #n ")" ::: "memory");  \
    __builtin_amdgcn_sched_barrier(0);                     \
  } while (0)

// ---------------- prepack: K/V f32 -> pre-swizzled bf16 LDS images ----------
// Tile T = ((b*4+n)*8+h)*8 + kt : 8192 bf16 (16 KB) per K image and V image.
// K image: img[key*128 + (d ^ ((key&7)<<3))] = K[key][d]
// V image: img[d*64  + (key ^ ((d&7)<<3))]  = V[key][d]
// Main kernel DMA-copies these images into LDS verbatim (global_load_lds).
__global__ __launch_bounds__(256, 4)
void prepack(const float* __restrict__ Kg, const float* __restrict__ Vg,
             bf16* __restrict__ Kws, bf16* __restrict__ Vws) {
  __shared__ __attribute__((aligned(16))) bf16 img[8192];
  const int t  = threadIdx.x;
  const int bk = blockIdx.x;
  const int kt = bk & 7, h = (bk >> 3) & 7, n = (bk >> 6) & 3, b = bk >> 8;
  const size_t rowbase = ((size_t)(b * kS + n * kChunk + kt * 64) * kHkv + h) * kD;

  // ---- K image ----
  const float* kp = Kg + rowbase;
#pragma unroll
  for (int it = 0; it < 8; ++it) {
    const int idx = it * 256 + t, key = idx >> 5, d4 = idx & 31;
    f32x4 v = *(const f32x4*)(kp + (size_t)key * kStrK + d4 * 4);
    bf16x4 kb;
#pragma unroll
    for (int j = 0; j < 4; ++j) kb[j] = (bf16)v[j];
    *(bf16x4*)&img[key * 128 + ((d4 * 4) ^ ((key & 7) << 3))] = kb;
  }
  __syncthreads();
  {
    bf16* dst = Kws + (size_t)bk * 8192;
#pragma unroll
    for (int i = 0; i < 4; ++i)
      *(bf16x8*)(dst + t * 8 + i * 2048) = *(const bf16x8*)(&img[t * 8 + i * 2048]);
  }
  __syncthreads();

  // ---- V image (transposed, swizzled; paired-key u32 writes) ----
  const float* vp = Vg + rowbase;
  const int vKp = t & 31, vD4h = t >> 5;
#pragma unroll
  for (int it = 0; it < 4; ++it) {
    const int d4 = 8 * it + vD4h;
    f32x4 va = *(const f32x4*)(vp + (size_t)(2 * vKp) * kStrK + d4 * 4);
    f32x4 vb = *(const f32x4*)(vp + (size_t)(2 * vKp + 1) * kStrK + d4 * 4);
#pragma unroll
    for (int j = 0; j < 4; ++j) {
      const int d = d4 * 4 + j;
      U32B uu; uu.h = bf16x2{(bf16)va[j], (bf16)vb[j]};
      *(unsigned*)&img[d * 64 + ((2 * vKp) ^ ((d & 7) << 3))] = uu.u;
    }
  }
  __syncthreads();
  {
    bf16* dst = Vws + (size_t)bk * 8192;
#pragma unroll
    for (int i = 0; i < 4; ++i)
      *(bf16x8*)(dst + t * 8 + i * 2048) = *(const bf16x8*)(&img[t * 8 + i * 2048]);
  }
}

// ---------------- main: R4 compute + DMA staging (global_load_lds) ----------
// 256 blocks (b,n,hq,p) x 512 threads (8 waves x 32 q-rows).
// Staging per phase: 4 x global_load_lds(16B) per wave. Counted vmcnt(4),
// raw s_barrier — next tile's DMA stays in flight across barriers (T4).
__global__ __launch_bounds__(512, 2)
void attn_main(const float* __restrict__ Qg, const bf16* __restrict__ Kws,
               const bf16* __restrict__ Vws, float* __restrict__ Og) {
  __shared__ __attribute__((aligned(16))) bf16 ldsK[2][8192];  // pre-swizzled image
  __shared__ __attribute__((aligned(16))) bf16 ldsV[2][8192];  // pre-swizzled image

  const int t = threadIdx.x, lane = t & 63, w = t >> 6;
  const int l31 = lane & 31, hi = lane >> 5;

  // XCD grouping: 32 blocks of one (b,n) per XCD (K/V L2-local).
  const int bid = blockIdx.x;
  const int gid = (bid & 7) * 32 + (bid >> 3);
  const int p = gid & 1, hq = (gid >> 1) & 15, n = (gid >> 5) & 3, b = (gid >> 7) & 1;
  const int h = hq >> 1;

  // Per-SIMD balanced strips: waves (w, w+4) need 9 tiles together.
  const int a      = (w < 4) ? (7 - 2 * w) : (2 * w - 8);
  const int need   = a + 1;
  const int strip  = 2 * a + p;
  const int qg     = n * kChunk + strip * 32 + l31;
  const int rowoff = 32 * p + l31;

  // ---- Q fragments: B-operand, col=q=l31, k = dk*16 + 8*hi + j ----
  bf16x8 qf[8];
  {
    const float* qp = Qg + ((size_t)(b * kS + qg) * kHq + hq) * kD;
#pragma unroll
    for (int dk = 0; dk < 8; ++dk) {
      f32x4 x0 = *(const f32x4*)(qp + dk * 16 + 8 * hi);
      f32x4 x1 = *(const f32x4*)(qp + dk * 16 + 8 * hi + 4);
      bf16x8 v;
#pragma unroll
      for (int q = 0; q < 4; ++q) { v[q] = (bf16)(x0[q] * kScale); v[4 + q] = (bf16)(x1[q] * kScale); }
      qf[dk] = v;
    }
  }

  f32x16 o[4];  // O^T accum: d = 32*dt + (r&3)+8*(r>>2)+4*hi, col q = l31
#pragma unroll
  for (int dt = 0; dt < 4; ++dt)
#pragma unroll
    for (int r = 0; r < 16; ++r) o[dt][r] = 0.f;
  float m = -1e30f, l = 0.f;

  // DMA staging: wave w copies image chunks {2w, 2w+1} of K and V (1KB each).
  const int tbase = ((b * 4 + n) * 8 + h) * 8;
  auto issueT = [&](int kt, int buf) {
    const bf16* kb = Kws + (size_t)(tbase + kt) * 8192;
    const bf16* vb = Vws + (size_t)(tbase + kt) * 8192;
#pragma unroll
    for (int c = 0; c < 2; ++c) {
      const int chunk = 2 * w + c;
      glds16(kb + chunk * 512 + lane * 8, &ldsK[buf][chunk * 512]);
      glds16(vb + chunk * 512 + lane * 8, &ldsV[buf][chunk * 512]);
    }
  };

  auto compute = [&](int buf, bool diag) {
    // ---- QK^T: S^T[key][q], 16 MFMA ----
    f32x16 s[2];
#pragma unroll
    for (int ks = 0; ks < 2; ++ks)
#pragma unroll
      for (int r = 0; r < 16; ++r) s[ks][r] = 0.f;
    __builtin_amdgcn_s_setprio(1);
#pragma unroll
    for (int ks = 0; ks < 2; ++ks) {
      const int key = ks * 32 + l31, swz = (key & 7) << 3;
      const bf16* kb = &ldsK[buf][key * 128];
#pragma unroll
      for (int dk = 0; dk < 8; ++dk) {
        bf16x8 kfr = *(const bf16x8*)&kb[(dk * 16 + 8 * hi) ^ swz];
        s[ks] = MFMA32(kfr, qf[dk], s[ks]);
      }
    }
    __builtin_amdgcn_s_setprio(0);
    if (diag) {
#pragma unroll
      for (int ks = 0; ks < 2; ++ks)
#pragma unroll
        for (int r = 0; r < 16; ++r) {
          const int key = ks * 32 + (r & 3) + 8 * (r >> 2) + 4 * hi;
          if (key > rowoff) s[ks][r] = -1e30f;
        }
    }
    // ---- lane-local softmax, exp2 domain (q = l31; partner = lane^32) ----
    float mx = -1e30f;
#pragma unroll
    for (int ks = 0; ks < 2; ++ks)
#pragma unroll
      for (int r = 0; r < 16; ++r) mx = fmaxf(mx, s[ks][r]);
    mx = fmaxf(mx, __shfl_xor(mx, 32, 64));
    if (__any(mx > m + kThr)) {  // T13 defer-max
      const float mn = fmaxf(m, mx), c = exp2f(m - mn);
      l *= c;
#pragma unroll
      for (int dt = 0; dt < 4; ++dt)
#pragma unroll
        for (int r = 0; r < 16; ++r) o[dt][r] *= c;
      m = mn;
    }
    unsigned u[2][8];
    float lp = 0.f;
#pragma unroll
    for (int ks = 0; ks < 2; ++ks)
#pragma unroll
      for (int q = 0; q < 8; ++q) {
        const float p0 = exp2f(s[ks][2 * q] - m), p1 = exp2f(s[ks][2 * q + 1] - m);
        lp += p0 + p1;
        U32B uu; uu.h = bf16x2{(bf16)p0, (bf16)p1};
        u[ks][q] = uu.u;
      }
    l += lp;
    // ---- half-exchange: interleaved-4 ownership -> contiguous-8 B-frags ----
    unsigned rc[2][4];
#pragma unroll
    for (int ks = 0; ks < 2; ++ks)
#pragma unroll
      for (int i = 0; i < 4; ++i)
        rc[ks][i] = (unsigned)__shfl_xor((int)u[ks][(i & 1) + 4 * (i >> 1) + (hi ? 0 : 2)], 32, 64);
    bf16x8 pa[4];
#pragma unroll
    for (int ks = 0; ks < 2; ++ks)
#pragma unroll
      for (int kh = 0; kh < 2; ++kh) {
        PAU pu;
        pu.u[0] = hi ? rc[ks][2 * kh]     : u[ks][4 * kh];
        pu.u[1] = hi ? rc[ks][2 * kh + 1] : u[ks][4 * kh + 1];
        pu.u[2] = hi ? u[ks][4 * kh + 2]  : rc[ks][2 * kh];
        pu.u[3] = hi ? u[ks][4 * kh + 3]  : rc[ks][2 * kh + 1];
        pa[ks * 2 + kh] = pu.v;
      }
    // ---- PV: O^T += V^T * P^T, 16 MFMA ----
    __builtin_amdgcn_s_setprio(1);
#pragma unroll
    for (int dt = 0; dt < 4; ++dt) {
      const int d = dt * 32 + l31, swz = (d & 7) << 3;
      const bf16* vbp = &ldsV[buf][d * 64];
#pragma unroll
      for (int ksl = 0; ksl < 4; ++ksl) {
        bf16x8 vfr = *(const bf16x8*)&vbp[(ksl * 16 + 8 * hi) ^ swz];
        o[dt] = MFMA32(vfr, pa[ksl], o[dt]);
      }
    }
    __builtin_amdgcn_s_setprio(0);
  };

  // ---- main loop: DMA pipeline, counted vmcnt, raw barriers ----
  issueT(0, 0);          // 4 gl_lds: tile 0
  issueT(1, 1);          // 4 gl_lds: tile 1 (stays in flight)
  VMWAIT(4);             // tile 0 landed (this wave)
  bar();                 // tile 0 landed (all waves)
#pragma unroll 1
  for (int kt = 0; kt < 8; ++kt) {
    if (kt < need) compute(kt & 1, kt + 1 == need);
    if (kt + 1 < 8) {
      bar();                               // all reads of buf kt&1 done
      if (kt + 2 < 8) {
        issueT(kt + 2, kt & 1);            // DMA next-next tile
        VMWAIT(4);                         // tile kt+1 landed (this wave)
      } else {
        VMWAIT(0);                         // last tile landed
      }
      bar();                               // tile kt+1 landed (all waves)
    }
  }

  // ---- epilogue: combine partner l, divide, store O^T regs ----
  l += __shfl_xor(l, 32, 64);
  const float inv = 1.f / l;
  float* op = Og + ((size_t)(b * kS + qg) * kHq + hq) * kD;
#pragma unroll
  for (int dt = 0; dt < 4; ++dt)
#pragma unroll
    for (int rq = 0; rq < 4; ++rq) {
      f32x4 st;
#pragma unroll
      for (int rr = 0; rr < 4; ++rr) st[rr] = o[dt][4 * rq + rr] * inv;
      *(f32x4*)(op + dt * 32 + 8 * rq + 4 * hi) = st;
    }
}

extern "C" void kernel_launch(void* const* d_in, const int* in_sizes, int n_in,
                              void* d_out, int out_size, void* d_ws, size_t ws_size,
                              hipStream_t stream) {
  (void)in_sizes; (void)n_in; (void)out_size; (void)ws_size;
  const float* Q = (const float*)d_in[0];
  const float* K = (const float*)d_in[1];
  const float* V = (const float*)d_in[2];
  float* O = (float*)d_out;
  bf16* Kws = (bf16*)d_ws;
  bf16* Vws = Kws + 512ull * 8192;  // 8 MB offset (ws >= 16 MB, verified R7)
  hipLaunchKernelGGL(prepack, dim3(512), dim3(256), 0, stream, K, V, Kws, Vws);
  hipLaunchKernelGGL(attn_main, dim3(256), dim3(512), 0, stream, Q, Kws, Vws, O);
}